// Round 9
// baseline (101.014 us; speedup 1.0000x reference)
//
#include <hip/hip_runtime.h>
#include <math.h>

#define BB 4
#define C 64
#define H 128
#define W 128
#define K 9
#define HW (H*W)
#define KC 576           // GEMM K dim: col = k*64 + c
#define OFFW 36          // offbuf row stride in f32 (2-way-conflict free)

typedef __attribute__((ext_vector_type(4))) float f32x4;
typedef __attribute__((ext_vector_type(8))) _Float16 f16x8;

static __device__ __forceinline__ f16x8 splat8(float f) {
  _Float16 h = (_Float16)f;
  f16x8 v = {h, h, h, h, h, h, h, h};
  return v;
}

// ---------------- kernel 1: transpose x,c to NHWC f16 + weight prep (folded)
__global__ __launch_bounds__(256) void xpose_prep_kernel(
    const float* __restrict__ x, const float* __restrict__ cin,
    const float* __restrict__ wd, const float* __restrict__ woff,
    _Float16* __restrict__ xt, _Float16* __restrict__ ct,
    _Float16* __restrict__ wtb, _Float16* __restrict__ wotb) {
  __shared__ _Float16 lds16[32 * 72];
  int t = threadIdx.x;

  if (blockIdx.y == 1 && blockIdx.x < 144) {
    int i = blockIdx.x * 256 + t;
    if (i < C * KC) {           // wtb [64][576] <- w_dcn, col = k*64+c
      int o = i / KC, r = i % KC, k = r >> 6, c = r & 63;
      wtb[i] = (_Float16)wd[(o * C + c) * 9 + k];
    }
    if (i < 32 * KC) {          // wotb [32][576] <- w_off, rows 27..31 = 0
      int o = i / KC, r = i % KC, t9 = r >> 6, c = r & 63;
      wotb[i] = (o < 27) ? (_Float16)woff[(o * C + c) * 9 + t9] : (_Float16)0.f;
    }
  }

  const float* src = blockIdx.y ? cin : x;
  _Float16* dst = blockIdx.y ? ct : xt;

  int P0 = blockIdx.x * 32;
  int b = P0 >> 14;
  int pp0 = P0 & (HW - 1);

  int p = t & 31;
  int cg = t >> 5;
  const float* xb = src + (size_t)b * C * HW + pp0 + p;
  f16x8 u;
#pragma unroll
  for (int j = 0; j < 8; ++j)
    u[j] = (_Float16)xb[(cg * 8 + j) * HW];
  *(f16x8*)(lds16 + p * 72 + ((cg ^ (p & 7)) << 3)) = u;

  __syncthreads();

  int q = t >> 3;
  int s = t & 7;
  f16x8 v = *(const f16x8*)(lds16 + q * 72 + ((s ^ (q & 7)) << 3));
  *(f16x8*)(dst + (size_t)(P0 + q) * 64 + s * 8) = v;
}

// ---------------- kernel 2: fused, waves independent, samples = B-fragments
// 256 thr = 4 waves; each wave owns 16 pixels end-to-end. LDS: offbuf only.
__global__ __launch_bounds__(256) void dcn_fused_kernel(
    const _Float16* __restrict__ xt, const _Float16* __restrict__ ct,
    const _Float16* __restrict__ wtb, const _Float16* __restrict__ wotb,
    const float* __restrict__ boff, const float* __restrict__ bd,
    float* __restrict__ out) {
  __shared__ float offbuf[4][16][OFFW];    // 9216 B

  int tid = threadIdx.x;
  int lane = tid & 63;
  int wv = __builtin_amdgcn_readfirstlane(tid >> 6);
  int lr = lane & 15;           // pixel index within wave AND fragment row/col
  int lh = lane >> 4;           // k-slot / o-subrow

  int pix0 = (blockIdx.x * 4 + wv) * 16;      // wave's 16 consecutive pixels
  int b   = pix0 >> 14;                        // uniform per wave
  int pp0 = pix0 & (HW - 1);
  int p   = pix0 + lr;
  int w = p & (W - 1);
  int h = (p >> 7) & (H - 1);

  const _Float16* ctb = ct + (size_t)b * HW * 64;
  const _Float16* xtb = xt + (size_t)b * HW * 64;

  // ======== GEMM1: off[32o][16p], B-frags loaded directly from ct ========
  f32x4 acc1a = {0.f, 0.f, 0.f, 0.f};
  f32x4 acc1b = {0.f, 0.f, 0.f, 0.f};
#pragma unroll 1
  for (int kb = 0; kb < 18; ++kb) {
    int t9 = kb >> 1;
    int cg = (kb & 1) * 4 + lh;
    int yy = h + t9 / 3 - 1;
    int xx = w + t9 % 3 - 1;
    bool ok = (yy >= 0) && (yy < H) && (xx >= 0) && (xx < W);
    int yc = min(max(yy, 0), H - 1), xc = min(max(xx, 0), W - 1);
    f16x8 bf = *(const f16x8*)(ctb + (size_t)(yc * W + xc) * 64 + cg * 8);
    if (!ok) bf = splat8(0.f);
    f16x8 a0 = *(const f16x8*)(wotb + (size_t)lr * KC + kb * 32 + lh * 8);
    f16x8 a1 = *(const f16x8*)(wotb + (size_t)(16 + lr) * KC + kb * 32 + lh * 8);
    acc1a = __builtin_amdgcn_mfma_f32_16x16x32_f16(a0, bf, acc1a, 0, 0, 0);
    acc1b = __builtin_amdgcn_mfma_f32_16x16x32_f16(a1, bf, acc1b, 0, 0, 0);
  }

  // write offbuf[wv][pixel][o]  (C/D: col=lr->pixel, row=lh*4+r->o)
  {
    f32x4 v0, v1;
#pragma unroll
    for (int r = 0; r < 4; ++r) {
      int o0 = lh * 4 + r;
      int o1 = 16 + lh * 4 + r;
      v0[r] = acc1a[r] + boff[o0];
      v1[r] = acc1b[r] + ((o1 < 27) ? boff[o1] : 0.f);
    }
    *(f32x4*)(&offbuf[wv][lr][lh * 4]) = v0;
    *(f32x4*)(&offbuf[wv][lr][16 + lh * 4]) = v1;
  }
  __syncthreads();

  // ======== sample + GEMM2: B-frag computed in registers per tap ========
  f32x4 acc[4];
#pragma unroll
  for (int i = 0; i < 4; ++i) acc[i] = (f32x4){0.f, 0.f, 0.f, 0.f};

#pragma unroll 1
  for (int k = 0; k < 9; ++k) {
    float dy = offbuf[wv][lr][2 * k];
    float dx = offbuf[wv][lr][2 * k + 1];
    float mv = offbuf[wv][lr][18 + k];
    float m = 1.0f / (1.0f + __expf(-mv));

    float py = (float)(h + k / 3 - 1) + dy;
    float px = (float)(w + k % 3 - 1) + dx;
    float y0f = floorf(py), x0f = floorf(px);
    int y0 = (int)y0f, x0 = (int)x0f;
    float wy1 = py - y0f, wx1 = px - x0f;
    float wy0 = 1.0f - wy1, wx0 = 1.0f - wx1;

    bool y0v = (y0 >= 0) && (y0 < H);
    bool y1v = (y0 + 1 >= 0) && (y0 + 1 < H);
    bool x0v = (x0 >= 0) && (x0 < W);
    bool x1v = (x0 + 1 >= 0) && (x0 + 1 < W);
    int y0c = min(max(y0, 0), H - 1), y1c = min(max(y0 + 1, 0), H - 1);
    int x0c = min(max(x0, 0), W - 1), x1c = min(max(x0 + 1, 0), W - 1);

    float w00 = wy0 * wx0 * (float)(y0v && x0v) * m;
    float w01 = wy0 * wx1 * (float)(y0v && x1v) * m;
    float w10 = wy1 * wx0 * (float)(y1v && x0v) * m;
    float w11 = wy1 * wx1 * (float)(y1v && x1v) * m;

    size_t i00 = (size_t)(y0c * W + x0c) * 64;
    size_t i01 = (size_t)(y0c * W + x1c) * 64;
    size_t i10 = (size_t)(y1c * W + x0c) * 64;
    size_t i11 = (size_t)(y1c * W + x1c) * 64;

#pragma unroll
    for (int half = 0; half < 2; ++half) {
      int cg = half * 4 + lh;
      int kb = 2 * k + half;

      f16x8 c00 = *(const f16x8*)(xtb + i00 + cg * 8);
      f16x8 c01 = *(const f16x8*)(xtb + i01 + cg * 8);
      f16x8 c10 = *(const f16x8*)(xtb + i10 + cg * 8);
      f16x8 c11 = *(const f16x8*)(xtb + i11 + cg * 8);

      f16x8 s = c00 * splat8(w00);
      s += c01 * splat8(w01);
      s += c10 * splat8(w10);
      s += c11 * splat8(w11);   // this IS the B-fragment for k-step kb

#pragma unroll
      for (int ot = 0; ot < 4; ++ot) {
        f16x8 a = *(const f16x8*)(wtb + (size_t)(ot * 16 + lr) * KC + kb * 32 + lh * 8);
        acc[ot] = __builtin_amdgcn_mfma_f32_16x16x32_f16(a, s, acc[ot], 0, 0, 0);
      }
    }
  }

  // ======== epilogue ========
#pragma unroll
  for (int ot = 0; ot < 4; ++ot) {
#pragma unroll
    for (int r = 0; r < 4; ++r) {
      int o = ot * 16 + lh * 4 + r;
      size_t base = ((size_t)(b * C + o)) * HW + pp0 + lr;
      out[base] = acc[ot][r] + bd[o];
    }
  }
}

extern "C" void kernel_launch(void* const* d_in, const int* in_sizes, int n_in,
                              void* d_out, int out_size, void* d_ws, size_t ws_size,
                              hipStream_t stream) {
  const float* x    = (const float*)d_in[0];
  const float* c    = (const float*)d_in[1];
  const float* woff = (const float*)d_in[2];
  const float* boff = (const float*)d_in[3];
  const float* wdcn = (const float*)d_in[4];
  const float* bdcn = (const float*)d_in[5];
  float* out = (float*)d_out;

  _Float16* xt   = (_Float16*)d_ws;                   // 4,194,304 f16
  _Float16* ct   = xt + 4194304;                      // 4,194,304 f16
  _Float16* wtb  = ct + 4194304;                      // 36,864 f16
  _Float16* wotb = wtb + 36864;                       // 18,432 f16

  int npix = BB * H * W;                              // 65536
  dim3 gx(npix / 32, 2);
  xpose_prep_kernel<<<gx, 256, 0, stream>>>(x, c, wdcn, woff, xt, ct, wtb, wotb);
  dcn_fused_kernel<<<npix / 64, 256, 0, stream>>>(xt, ct, wtb, wotb, boff, bdcn, out);
}

// Round 10
// 42.601 us; speedup vs baseline: 2.3711x; 2.3711x over previous
//
#include <hip/hip_runtime.h>
#include <math.h>

#define BB 4
#define C 64
#define H 128
#define W 128
#define HW (H*W)
#define KC 576            // GEMM K dim: col = k*64 + c
#define WROWS 8           // x-window rows
#define WCOLS 40          // x-window cols
#define CROWS 4           // c-window rows
#define CCOLS 34          // c-window cols

typedef __attribute__((ext_vector_type(4))) float f32x4;
typedef __attribute__((ext_vector_type(8))) _Float16 f16x8;

static __device__ __forceinline__ f16x8 splat8(float f) {
  _Float16 h = (_Float16)f;
  f16x8 v = {h, h, h, h, h, h, h, h};
  return v;
}

// ---------------- kernel 1: transpose x,c to NHWC f16 + frag-major weight prep
__global__ __launch_bounds__(256) void xpose_prep_kernel(
    const float* __restrict__ x, const float* __restrict__ cin,
    const float* __restrict__ wd, const float* __restrict__ woff,
    _Float16* __restrict__ xt, _Float16* __restrict__ ct,
    _Float16* __restrict__ wtbf, _Float16* __restrict__ wotf) {
  __shared__ _Float16 lds16[32 * 72];
  int t = threadIdx.x;

  if (blockIdx.y == 1 && blockIdx.x < 144) {
    int i = blockIdx.x * 256 + t;          // 0..36863
    {  // wtbf: [kb*4+ot][lane][8] <- w_dcn; value = A-frag elem of R9's load
      int j = i & 7, ln = (i >> 3) & 63, fi = i >> 9;   // fi 0..71
      int ot = fi & 3, kb = fi >> 2;
      int o = ot * 16 + (ln & 15);
      int kcol = kb * 32 + (ln >> 4) * 8 + j;
      int k = kcol >> 6, cc = kcol & 63;
      wtbf[i] = (_Float16)wd[(o * C + cc) * 9 + k];
    }
    if (i < 32 * KC) {  // wotf: [kb*2+ot2][lane][8] <- w_off (rows>=27 -> 0)
      int j = i & 7, ln = (i >> 3) & 63, fi = i >> 9;   // fi 0..35
      int ot2 = fi & 1, kb = fi >> 1;
      int o = ot2 * 16 + (ln & 15);
      int kcol = kb * 32 + (ln >> 4) * 8 + j;
      int k = kcol >> 6, cc = kcol & 63;
      wotf[i] = (o < 27) ? (_Float16)woff[(o * C + cc) * 9 + k] : (_Float16)0.f;
    }
  }

  const float* src = blockIdx.y ? cin : x;
  _Float16* dst = blockIdx.y ? ct : xt;

  int P0 = blockIdx.x * 32;
  int b = P0 >> 14;
  int pp0 = P0 & (HW - 1);

  int p = t & 31;
  int cg = t >> 5;
  const float* xb = src + (size_t)b * C * HW + pp0 + p;
  f16x8 u;
#pragma unroll
  for (int j = 0; j < 8; ++j)
    u[j] = (_Float16)xb[(cg * 8 + j) * HW];
  *(f16x8*)(lds16 + p * 72 + ((cg ^ (p & 7)) << 3)) = u;

  __syncthreads();

  int q = t >> 3;
  int s = t & 7;
  f16x8 v = *(const f16x8*)(lds16 + q * 72 + ((s ^ (q & 7)) << 3));
  *(f16x8*)(dst + (size_t)(P0 + q) * 64 + s * 8) = v;
}

// ---------------- kernel 2: fused DCN, LDS-windowed sampling, 2 barriers
// block = 64 px (2 rows x 32 cols), 4 waves; wave owns 16 px end-to-end.
__global__ __launch_bounds__(256) void dcn_fused_kernel(
    const _Float16* __restrict__ xt, const _Float16* __restrict__ ct,
    const _Float16* __restrict__ wtbf, const _Float16* __restrict__ wotf,
    const float* __restrict__ boff, const float* __restrict__ bd,
    float* __restrict__ out) {
  __shared__ _Float16 win[WROWS * WCOLS * 64];   // 40960 B (c-window overlays)
  __shared__ float offbuf[4][16][36];            // 9216 B

  int tid = threadIdx.x;
  int bid = blockIdx.x;
  int w0 = (bid & 3) * 32;
  int h0 = ((bid >> 2) & 63) * 2;
  int b  = bid >> 8;

  int lane = tid & 63;
  int wv = tid >> 6;
  int lr = lane & 15, lh = lane >> 4;
  int h   = h0 + (wv >> 1);                      // wave-uniform row
  int wpx = w0 + (wv & 1) * 16 + lr;             // lane's pixel col

  const _Float16* xtb = xt + (size_t)b * HW * 64;
  const _Float16* ctb = ct + (size_t)b * HW * 64;

  int crlo = min(max(h0 - 1, 0), H - CROWS);
  int cclo = min(max(w0 - 1, 0), W - CCOLS);
  int rlo  = min(max(h0 - 3, 0), H - WROWS);
  int clo  = min(max(w0 - 4, 0), W - WCOLS);

  // swizzled window accessors: slot = cg ^ (pix&7)
  auto rdwin = [&](int iy, int ix, int cg) -> f16x8 {
    int pix = iy * WCOLS + ix;
    return *(const f16x8*)(win + (size_t)pix * 64 + ((cg ^ (pix & 7)) << 3));
  };
  auto rdcwin = [&](int iy, int ix, int cg) -> f16x8 {
    int pix = iy * CCOLS + ix;
    return *(const f16x8*)(win + (size_t)pix * 64 + ((cg ^ (pix & 7)) << 3));
  };

  // ---- stage c-window (rows crlo.., 34 cols), coalesced full lines ----
#pragma unroll
  for (int sweep = 0; sweep < 5; ++sweep) {
    int cch = sweep * 256 + tid;                 // 16-B chunks, 1088 total
    if (cch < CROWS * CCOLS * 8) {
      int row = cch / (CCOLS * 8);
      int rem = cch - row * (CCOLS * 8);
      int col = rem >> 3, part = rem & 7;
      int pix = cch >> 3;
      *(f16x8*)(win + (size_t)pix * 64 + ((part ^ (pix & 7)) << 3)) =
        *(const f16x8*)(ctb + ((size_t)(crlo + row) * W + cclo + col) * 64 + part * 8);
    }
  }
  __syncthreads();

  // ---- GEMM1: off[32o][16px] ; B-frag from c-window, A coalesced ----
  f32x4 acc1a = {0.f, 0.f, 0.f, 0.f};
  f32x4 acc1b = {0.f, 0.f, 0.f, 0.f};
#pragma unroll 2
  for (int kb = 0; kb < 18; ++kb) {
    int t9 = kb >> 1;
    int cg = (kb & 1) * 4 + lh;
    int ty = h + t9 / 3 - 1;
    int tx = wpx + t9 % 3 - 1;
    bool okv = (ty >= 0) && (ty < H) && (tx >= 0) && (tx < W);
    int iy = min(max(ty, 0), H - 1) - crlo;
    int ix = min(max(tx, 0), W - 1) - cclo;
    f16x8 bf = rdcwin(iy, ix, cg);
    if (!okv) bf = splat8(0.f);
    f16x8 a0 = *(const f16x8*)(wotf + ((size_t)(kb * 2 + 0) * 64 + lane) * 8);
    f16x8 a1 = *(const f16x8*)(wotf + ((size_t)(kb * 2 + 1) * 64 + lane) * 8);
    acc1a = __builtin_amdgcn_mfma_f32_16x16x32_f16(a0, bf, acc1a, 0, 0, 0);
    acc1b = __builtin_amdgcn_mfma_f32_16x16x32_f16(a1, bf, acc1b, 0, 0, 0);
  }

  // offbuf[wave][pixel][o] = acc + bias  (C/D: col=lr->pixel, row=lh*4+r->o)
  {
    f32x4 v0, v1;
#pragma unroll
    for (int r = 0; r < 4; ++r) {
      int o0 = lh * 4 + r;
      int o1 = 16 + lh * 4 + r;
      v0[r] = acc1a[r] + boff[o0];
      v1[r] = acc1b[r] + ((o1 < 27) ? boff[o1] : 0.f);
    }
    *(f32x4*)(&offbuf[wv][lr][lh * 4]) = v0;
    *(f32x4*)(&offbuf[wv][lr][16 + lh * 4]) = v1;
  }
  __syncthreads();   // all c-window reads done; offbuf visible; overwrite win

  // ---- stage x-window (8 rows x 40 cols), coalesced full lines ----
#pragma unroll
  for (int sweep = 0; sweep < 10; ++sweep) {
    int cch = sweep * 256 + tid;                 // 2560 chunks
    int row = cch / (WCOLS * 8);
    int rem = cch - row * (WCOLS * 8);
    int col = rem >> 3, part = rem & 7;
    int pix = cch >> 3;
    *(f16x8*)(win + (size_t)pix * 64 + ((part ^ (pix & 7)) << 3)) =
      *(const f16x8*)(xtb + ((size_t)(rlo + row) * W + clo + col) * 64 + part * 8);
  }
  __syncthreads();

  // ---- sample + GEMM2: B-frag in registers from window; A coalesced ----
  f32x4 acc[4];
#pragma unroll
  for (int i = 0; i < 4; ++i) acc[i] = (f32x4){0.f, 0.f, 0.f, 0.f};

#pragma unroll 1
  for (int k = 0; k < 9; ++k) {
    float dy = offbuf[wv][lr][2 * k];
    float dx = offbuf[wv][lr][2 * k + 1];
    float mv = offbuf[wv][lr][18 + k];
    float m = 1.0f / (1.0f + __expf(-mv));

    float py = (float)(h + k / 3 - 1) + dy;
    float px = (float)(wpx + k % 3 - 1) + dx;
    float y0f = floorf(py), x0f = floorf(px);
    int y0 = (int)y0f, x0 = (int)x0f;
    float wy1 = py - y0f, wx1 = px - x0f;
    float wy0 = 1.0f - wy1, wx0 = 1.0f - wx1;

    bool y0v = (y0 >= 0) && (y0 < H);
    bool y1v = (y0 + 1 >= 0) && (y0 + 1 < H);
    bool x0v = (x0 >= 0) && (x0 < W);
    bool x1v = (x0 + 1 >= 0) && (x0 + 1 < W);
    int y0c = min(max(y0, 0), H - 1), y1c = min(max(y0 + 1, 0), H - 1);
    int x0c = min(max(x0, 0), W - 1), x1c = min(max(x0 + 1, 0), W - 1);

    float w00 = wy0 * wx0 * (float)(y0v && x0v) * m;
    float w01 = wy0 * wx1 * (float)(y0v && x1v) * m;
    float w10 = wy1 * wx0 * (float)(y1v && x0v) * m;
    float w11 = wy1 * wx1 * (float)(y1v && x1v) * m;

    int iy0 = y0c - rlo, iy1 = y1c - rlo;
    int ix0 = x0c - clo, ix1 = x1c - clo;
    bool inY0 = (unsigned)iy0 < WROWS, inY1 = (unsigned)iy1 < WROWS;
    bool inX0 = (unsigned)ix0 < WCOLS, inX1 = (unsigned)ix1 < WCOLS;
    bool in00 = inY0 && inX0, in01 = inY0 && inX1;
    bool in10 = inY1 && inX0, in11 = inY1 && inX1;
    int jy0 = min(max(iy0, 0), WROWS - 1), jy1 = min(max(iy1, 0), WROWS - 1);
    int jx0 = min(max(ix0, 0), WCOLS - 1), jx1 = min(max(ix1, 0), WCOLS - 1);

#pragma unroll
    for (int half = 0; half < 2; ++half) {
      int cg = half * 4 + lh;
      f16x8 c00 = rdwin(jy0, jx0, cg);
      f16x8 c01 = rdwin(jy0, jx1, cg);
      f16x8 c10 = rdwin(jy1, jx0, cg);
      f16x8 c11 = rdwin(jy1, jx1, cg);
      // rare fallback: offset pushed sample outside staged window
      if (!in00) c00 = *(const f16x8*)(xtb + ((size_t)y0c * W + x0c) * 64 + cg * 8);
      if (!in01) c01 = *(const f16x8*)(xtb + ((size_t)y0c * W + x1c) * 64 + cg * 8);
      if (!in10) c10 = *(const f16x8*)(xtb + ((size_t)y1c * W + x0c) * 64 + cg * 8);
      if (!in11) c11 = *(const f16x8*)(xtb + ((size_t)y1c * W + x1c) * 64 + cg * 8);

      f16x8 s = c00 * splat8(w00);
      s += c01 * splat8(w01);
      s += c10 * splat8(w10);
      s += c11 * splat8(w11);          // this IS the B-fragment for kb

      int kb = 2 * k + half;
#pragma unroll
      for (int ot = 0; ot < 4; ++ot) {
        f16x8 a = *(const f16x8*)(wtbf + ((size_t)(kb * 4 + ot) * 64 + lane) * 8);
        acc[ot] = __builtin_amdgcn_mfma_f32_16x16x32_f16(a, s, acc[ot], 0, 0, 0);
      }
    }
  }

  // ---- epilogue ----
#pragma unroll
  for (int ot = 0; ot < 4; ++ot) {
#pragma unroll
    for (int r = 0; r < 4; ++r) {
      int o = ot * 16 + lh * 4 + r;
      size_t base = ((size_t)(b * C + o)) * HW + (size_t)h * W + w0 + (wv & 1) * 16 + lr;
      out[base] = acc[ot][r] + bd[o];
    }
  }
}

extern "C" void kernel_launch(void* const* d_in, const int* in_sizes, int n_in,
                              void* d_out, int out_size, void* d_ws, size_t ws_size,
                              hipStream_t stream) {
  const float* x    = (const float*)d_in[0];
  const float* c    = (const float*)d_in[1];
  const float* woff = (const float*)d_in[2];
  const float* boff = (const float*)d_in[3];
  const float* wdcn = (const float*)d_in[4];
  const float* bdcn = (const float*)d_in[5];
  float* out = (float*)d_out;

  _Float16* xt   = (_Float16*)d_ws;                   // 4,194,304 f16
  _Float16* ct   = xt + 4194304;                      // 4,194,304 f16
  _Float16* wtbf = ct + 4194304;                      // 36,864 f16
  _Float16* wotf = wtbf + 36864;                      // 18,432 f16

  int npix = BB * H * W;                              // 65536
  dim3 gx(npix / 32, 2);
  xpose_prep_kernel<<<gx, 256, 0, stream>>>(x, c, wdcn, woff, xt, ct, wtbf, wotf);
  dcn_fused_kernel<<<npix / 64, 256, 0, stream>>>(xt, ct, wtbf, wotf, boff, bdcn, out);
}